// Round 1
// baseline (612.609 us; speedup 1.0000x reference)
//
#include <hip/hip_runtime.h>

// HeteroGraphSage on MI355X.
// Key algebra: only acct_out is returned, so the entire merchant head (proj_m,
// lin_am scatter, h_m) is dead. Remaining graph folded to:
//   neigh64[a]  = sum_e w_e * x_m[src_e]   (64-dim, raw merchant feats)
//   sumw[a]     = sum_e w_e
//   h_a = relu( (Wc1@Wp_a) x_a + (Wc2@Wr_ma) neigh64 + sumw*(Wc2@br_ma)
//               + bc_a + Wc1@bp_a )
//   out = sigmoid(Wo . h_a + bo)

typedef __attribute__((ext_vector_type(8))) short short8;
typedef __attribute__((ext_vector_type(4))) float f32x4;

__device__ inline unsigned short f32_bf16(float f) {
  unsigned int u = __float_as_uint(f);
  u += 0x7FFF + ((u >> 16) & 1);   // round-to-nearest-even
  return (unsigned short)(u >> 16);
}

// ---- weight folding: 128 blocks (one per output col), 192 threads (one per k)
__global__ void prep_kernel(const float* __restrict__ Wp_a, const float* __restrict__ bp_a,
                            const float* __restrict__ Wr_ma, const float* __restrict__ br_ma,
                            const float* __restrict__ Wc_a, const float* __restrict__ bc_a,
                            unsigned short* __restrict__ Wcomb, float* __restrict__ beff,
                            float* __restrict__ vbr) {
  int col = blockIdx.x;
  int k = threadIdx.x;           // 0..191: k<128 -> x path, k>=128 -> neigh path
  const float* wc = Wc_a + col * 256;
  float acc = 0.f;
  if (k < 128) {
    for (int j = 0; j < 128; ++j) acc += wc[j] * Wp_a[j * 128 + k];
  } else {
    int kk = k - 128;
    for (int j = 0; j < 128; ++j) acc += wc[128 + j] * Wr_ma[j * 64 + kk];
  }
  Wcomb[col * 192 + k] = f32_bf16(acc);
  if (k == 0) {
    float b = bc_a[col];
    for (int j = 0; j < 128; ++j) b += wc[j] * bp_a[j];
    beff[col] = b;
  } else if (k == 1) {
    float v = 0.f;
    for (int j = 0; j < 128; ++j) v += wc[128 + j] * br_ma[j];
    vbr[col] = v;
  }
}

// ---- edge scatter: one wave per edge, lane i handles feature i (64 feats)
__global__ void edge_kernel(const float* __restrict__ xm,
                            const int* __restrict__ src, const int* __restrict__ dst,
                            const float* __restrict__ w,
                            float* __restrict__ neigh, float* __restrict__ sumw, int E) {
  int idx = blockIdx.x * blockDim.x + threadIdx.x;
  int e = idx >> 6;
  int lane = idx & 63;
  if (e >= E) return;
  int s = src[e], d = dst[e];
  float we = w[e];
  float v = xm[s * 64 + lane] * we;
  atomicAdd(&neigh[d * 64 + lane], v);
  if (lane == 0) atomicAdd(&sumw[d], we);
}

// ---- fused account GEMM + head: 64 rows/block, 4 waves, 16x16x32 bf16 MFMA
// A = [x_a | neigh64] (K=192, bf16 in LDS), B = Wcomb [col][k] row-major.
__global__ __launch_bounds__(256) void acct_kernel(
    const float* __restrict__ xa, const float* __restrict__ neigh,
    const float* __restrict__ sumw, const unsigned short* __restrict__ Wcomb,
    const float* __restrict__ beff, const float* __restrict__ vbr,
    const float* __restrict__ Wo, const float* __restrict__ bo,
    float* __restrict__ out, int NA) {
  __shared__ unsigned int A_lds[64 * 100];   // 96 bf16-pairs/row + 4 pad (16B-aligned rows)
  int tid = threadIdx.x;
  int r0 = blockIdx.x * 64;

  // stage A tile: f32 -> bf16 pairs
  for (int i = tid; i < 64 * 96; i += 256) {
    int row = i / 96, p = i - row * 96;   // pair p covers k=2p,2p+1
    int grow = r0 + row;
    float2 v = make_float2(0.f, 0.f);
    if (grow < NA) {
      if (p < 64) v = ((const float2*)xa)[(size_t)grow * 64 + p];
      else        v = ((const float2*)neigh)[(size_t)grow * 32 + (p - 64)];
    }
    unsigned int lo = f32_bf16(v.x);
    unsigned int hi = f32_bf16(v.y);
    A_lds[row * 100 + p] = lo | (hi << 16);
  }
  __syncthreads();

  int wave = tid >> 6, lane = tid & 63;
  int lane15 = lane & 15, quad = lane >> 4;

  f32x4 acc[8];
#pragma unroll
  for (int t = 0; t < 8; ++t) acc[t] = (f32x4){0.f, 0.f, 0.f, 0.f};

  // A frag: A[m=lane&15][k=quad*8+j]; B frag: B^T[n=lane&15][k=quad*8+j] = Wcomb row
  const unsigned int* abase = &A_lds[(wave * 16 + lane15) * 100 + quad * 4];
#pragma unroll
  for (int s = 0; s < 6; ++s) {
    union { uint4 u; short8 h; } af;
    af.u = *((const uint4*)(abase + s * 16));
#pragma unroll
    for (int t = 0; t < 8; ++t) {
      union { uint4 u; short8 h; } bf;
      bf.u = *((const uint4*)(Wcomb + (t * 16 + lane15) * 192 + s * 32 + quad * 8));
      acc[t] = __builtin_amdgcn_mfma_f32_16x16x32_bf16(af.h, bf.h, acc[t], 0, 0, 0);
    }
  }

  // epilogue: h=relu(acc + beff + sumw*vbr); out=sigmoid(h.Wo + bo)
  // C/D layout: col = t*16 + (lane&15), row = quad*4 + reg   [m89/m91 verified]
  float bo0 = bo[0];
  float sw[4];
#pragma unroll
  for (int r = 0; r < 4; ++r) {
    int grow = r0 + wave * 16 + quad * 4 + r;
    sw[r] = (grow < NA) ? sumw[grow] : 0.f;
  }
  float rowsum[4] = {0.f, 0.f, 0.f, 0.f};
#pragma unroll
  for (int t = 0; t < 8; ++t) {
    int col = t * 16 + lane15;
    float be = beff[col], vb = vbr[col], wo = Wo[col];
#pragma unroll
    for (int r = 0; r < 4; ++r) {
      float h = acc[t][r] + be + sw[r] * vb;
      h = fmaxf(h, 0.f);
      rowsum[r] += h * wo;
    }
  }
  // reduce across the 16 lanes (lane&15) holding different col subsets
#pragma unroll
  for (int m = 1; m <= 8; m <<= 1) {
#pragma unroll
    for (int r = 0; r < 4; ++r) rowsum[r] += __shfl_xor(rowsum[r], m, 64);
  }
  if (lane15 == 0) {
#pragma unroll
    for (int r = 0; r < 4; ++r) {
      int grow = r0 + wave * 16 + quad * 4 + r;
      if (grow < NA) out[grow] = 1.0f / (1.0f + __expf(-(rowsum[r] + bo0)));
    }
  }
}

extern "C" void kernel_launch(void* const* d_in, const int* in_sizes, int n_in,
                              void* d_out, int out_size, void* d_ws, size_t ws_size,
                              hipStream_t stream) {
  const float* xa      = (const float*)d_in[0];
  const float* xm      = (const float*)d_in[1];
  const int*   ema_src = (const int*)d_in[5];
  const int*   ema_dst = (const int*)d_in[6];
  const float* ema_w   = (const float*)d_in[7];
  const float* Wp_a    = (const float*)d_in[8];
  const float* bp_a    = (const float*)d_in[9];
  const float* Wr_ma   = (const float*)d_in[14];
  const float* br_ma   = (const float*)d_in[15];
  const float* Wc_a    = (const float*)d_in[16];
  const float* bc_a    = (const float*)d_in[17];
  const float* Wo      = (const float*)d_in[20];
  const float* bo      = (const float*)d_in[21];

  int NA = in_sizes[0] / 128;
  int E  = in_sizes[5];

  char* ws = (char*)d_ws;
  float* neigh = (float*)ws;                       // NA x 64
  float* sumw  = neigh + (size_t)NA * 64;          // NA
  size_t off = (((size_t)NA * 65 * 4) + 255) & ~(size_t)255;
  unsigned short* Wcomb = (unsigned short*)(ws + off);   // 128 x 192 bf16
  float* beff = (float*)(ws + off + 128 * 192 * 2);
  float* vbr  = beff + 128;

  hipMemsetAsync(neigh, 0, (size_t)NA * 65 * 4, stream);
  prep_kernel<<<128, 192, 0, stream>>>(Wp_a, bp_a, Wr_ma, br_ma, Wc_a, bc_a, Wcomb, beff, vbr);

  int eb = (E * 64 + 255) / 256;
  edge_kernel<<<eb, 256, 0, stream>>>(xm, ema_src, ema_dst, ema_w, neigh, sumw, E);

  int ab = (NA + 63) / 64;
  acct_kernel<<<ab, 256, 0, stream>>>(xa, neigh, sumw, Wcomb, beff, vbr, Wo, bo,
                                      (float*)d_out, NA);
}

// Round 2
// 575.558 us; speedup vs baseline: 1.0644x; 1.0644x over previous
//
#include <hip/hip_runtime.h>

// HeteroGraphSage on MI355X — round 2: CSR counting-sort + gather (no f32 atomics).
// Algebra (merchant head is dead code):
//   neigh64[a] = sum_e w_e * x_m[src_e] ; sumw[a] = sum_e w_e
//   h_a = relu( Wcomb @ [x_a | neigh64] + sumw*vbr + beff )
//   out = sigmoid(Wo . h_a + bo)

typedef __attribute__((ext_vector_type(8))) short short8;
typedef __attribute__((ext_vector_type(4))) float f32x4;

__device__ inline unsigned short f32_bf16(float f) {
  unsigned int u = __float_as_uint(f);
  u += 0x7FFF + ((u >> 16) & 1);   // round-to-nearest-even
  return (unsigned short)(u >> 16);
}

// ---- weight folding: 128 blocks (one per output col), 192 threads (one per k)
__global__ void prep_kernel(const float* __restrict__ Wp_a, const float* __restrict__ bp_a,
                            const float* __restrict__ Wr_ma, const float* __restrict__ br_ma,
                            const float* __restrict__ Wc_a, const float* __restrict__ bc_a,
                            unsigned short* __restrict__ Wcomb, float* __restrict__ beff,
                            float* __restrict__ vbr) {
  int col = blockIdx.x;
  int k = threadIdx.x;           // 0..191: k<128 -> x path, k>=128 -> neigh path
  const float* wc = Wc_a + col * 256;
  float acc = 0.f;
  if (k < 128) {
    for (int j = 0; j < 128; ++j) acc += wc[j] * Wp_a[j * 128 + k];
  } else {
    int kk = k - 128;
    for (int j = 0; j < 128; ++j) acc += wc[128 + j] * Wr_ma[j * 64 + kk];
  }
  Wcomb[col * 192 + k] = f32_bf16(acc);
  if (k == 0) {
    float b = bc_a[col];
    for (int j = 0; j < 128; ++j) b += wc[j] * bp_a[j];
    beff[col] = b;
  } else if (k == 1) {
    float v = 0.f;
    for (int j = 0; j < 128; ++j) v += wc[128 + j] * br_ma[j];
    vbr[col] = v;
  }
}

// ---- CSR build: histogram, 3-phase exclusive scan, scatter ------------------
__global__ void hist_kernel(const int* __restrict__ dst, int* __restrict__ counts, int E) {
  int e = blockIdx.x * 256 + threadIdx.x;
  if (e < E) atomicAdd(&counts[dst[e]], 1);
}

__global__ void scan_a(const int* __restrict__ counts, int* __restrict__ bsum, int NA) {
  __shared__ int tmp[256];
  int t = threadIdx.x;
  int i = blockIdx.x * 256 + t;
  tmp[t] = (i < NA) ? counts[i] : 0;
  __syncthreads();
  for (int off = 128; off > 0; off >>= 1) {
    if (t < off) tmp[t] += tmp[t + off];
    __syncthreads();
  }
  if (t == 0) bsum[blockIdx.x] = tmp[0];
}

__global__ void scan_b(const int* __restrict__ bsum, int* __restrict__ bexcl, int nb) {
  __shared__ int tmp[1024];
  int t = threadIdx.x;
  int v = (t < nb) ? bsum[t] : 0;
  tmp[t] = v;
  __syncthreads();
  for (int off = 1; off < 1024; off <<= 1) {
    int x = (t >= off) ? tmp[t - off] : 0;
    __syncthreads();
    tmp[t] += x;
    __syncthreads();
  }
  bexcl[t] = tmp[t] - v;   // exclusive
}

__global__ void scan_c(const int* __restrict__ counts, const int* __restrict__ bexcl,
                       int* __restrict__ rowstart, int* __restrict__ cursor, int NA) {
  __shared__ int tmp[256];
  int t = threadIdx.x;
  int i = blockIdx.x * 256 + t;
  int v = (i < NA) ? counts[i] : 0;
  tmp[t] = v;
  __syncthreads();
  for (int off = 1; off < 256; off <<= 1) {
    int x = (t >= off) ? tmp[t - off] : 0;
    __syncthreads();
    tmp[t] += x;
    __syncthreads();
  }
  int excl = bexcl[blockIdx.x] + tmp[t] - v;
  if (i < NA) { rowstart[i] = excl; cursor[i] = excl; }
  else if (i == NA) { rowstart[NA] = excl; }   // == E (all tail counts are 0)
}

__global__ void scatter_kernel(const int* __restrict__ src, const int* __restrict__ dst,
                               const float* __restrict__ w, int* __restrict__ cursor,
                               unsigned long long* __restrict__ edges, int E) {
  int e = blockIdx.x * 256 + threadIdx.x;
  if (e >= E) return;
  int d = dst[e];
  int pos = atomicAdd(&cursor[d], 1);
  unsigned long long pk = (unsigned int)src[e] |
                          ((unsigned long long)__float_as_uint(w[e]) << 32);
  edges[pos] = pk;
}

// ---- neigh gather: one wave per account row, lane = feature ----------------
__global__ __launch_bounds__(256) void gather_kernel(
    const float* __restrict__ xm, const unsigned long long* __restrict__ edges,
    const int* __restrict__ rowstart, unsigned int* __restrict__ neighbf,
    float* __restrict__ sumw, int NA) {
  int wave = threadIdx.x >> 6, lane = threadIdx.x & 63;
  int a = blockIdx.x * 4 + wave;
  if (a >= NA) return;
  int s0 = rowstart[a], s1 = rowstart[a + 1];
  float acc = 0.f, ws = 0.f;
  for (int e = s0; e < s1; ++e) {
    unsigned long long pk = edges[e];           // broadcast (same addr all lanes)
    int s = (int)(pk & 0xffffffffu);
    float we = __uint_as_float((unsigned int)(pk >> 32));
    ws += we;
    acc += we * xm[(size_t)s * 64 + lane];
  }
  float hi = __shfl_xor(acc, 1, 64);            // even lane <- odd partner
  if ((lane & 1) == 0) {
    unsigned int pk2 = (unsigned int)f32_bf16(acc) |
                       ((unsigned int)f32_bf16(hi) << 16);
    neighbf[(size_t)a * 32 + (lane >> 1)] = pk2;
  }
  if (lane == 0) sumw[a] = ws;
}

// ---- fused account GEMM + head: 64 rows/block, 4 waves, 16x16x32 bf16 MFMA
__global__ __launch_bounds__(256) void acct_kernel(
    const float* __restrict__ xa, const unsigned int* __restrict__ neighbf,
    const float* __restrict__ sumw, const unsigned short* __restrict__ Wcomb,
    const float* __restrict__ beff, const float* __restrict__ vbr,
    const float* __restrict__ Wo, const float* __restrict__ bo,
    float* __restrict__ out, int NA) {
  __shared__ unsigned int A_lds[64 * 100];   // 96 bf16-pairs/row + 4 pad
  int tid = threadIdx.x;
  int r0 = blockIdx.x * 64;

  for (int i = tid; i < 64 * 96; i += 256) {
    int row = i / 96, p = i - row * 96;   // pair p covers k=2p,2p+1
    int grow = r0 + row;
    unsigned int packed = 0;
    if (grow < NA) {
      if (p < 64) {
        float2 v = ((const float2*)xa)[(size_t)grow * 64 + p];
        packed = (unsigned int)f32_bf16(v.x) | ((unsigned int)f32_bf16(v.y) << 16);
      } else {
        packed = neighbf[(size_t)grow * 32 + (p - 64)];
      }
    }
    A_lds[row * 100 + p] = packed;
  }
  __syncthreads();

  int wave = tid >> 6, lane = tid & 63;
  int lane15 = lane & 15, quad = lane >> 4;

  f32x4 acc[8];
#pragma unroll
  for (int t = 0; t < 8; ++t) acc[t] = (f32x4){0.f, 0.f, 0.f, 0.f};

  const unsigned int* abase = &A_lds[(wave * 16 + lane15) * 100 + quad * 4];
#pragma unroll
  for (int s = 0; s < 6; ++s) {
    union { uint4 u; short8 h; } af;
    af.u = *((const uint4*)(abase + s * 16));
#pragma unroll
    for (int t = 0; t < 8; ++t) {
      union { uint4 u; short8 h; } bf;
      bf.u = *((const uint4*)(Wcomb + (t * 16 + lane15) * 192 + s * 32 + quad * 8));
      acc[t] = __builtin_amdgcn_mfma_f32_16x16x32_bf16(af.h, bf.h, acc[t], 0, 0, 0);
    }
  }

  // epilogue: C/D layout col = t*16 + (lane&15), row = quad*4 + reg
  float bo0 = bo[0];
  float sw[4];
#pragma unroll
  for (int r = 0; r < 4; ++r) {
    int grow = r0 + wave * 16 + quad * 4 + r;
    sw[r] = (grow < NA) ? sumw[grow] : 0.f;
  }
  float rowsum[4] = {0.f, 0.f, 0.f, 0.f};
#pragma unroll
  for (int t = 0; t < 8; ++t) {
    int col = t * 16 + lane15;
    float be = beff[col], vb = vbr[col], wo = Wo[col];
#pragma unroll
    for (int r = 0; r < 4; ++r) {
      float h = acc[t][r] + be + sw[r] * vb;
      h = fmaxf(h, 0.f);
      rowsum[r] += h * wo;
    }
  }
#pragma unroll
  for (int m = 1; m <= 8; m <<= 1) {
#pragma unroll
    for (int r = 0; r < 4; ++r) rowsum[r] += __shfl_xor(rowsum[r], m, 64);
  }
  if (lane15 == 0) {
#pragma unroll
    for (int r = 0; r < 4; ++r) {
      int grow = r0 + wave * 16 + quad * 4 + r;
      if (grow < NA) out[grow] = 1.0f / (1.0f + __expf(-(rowsum[r] + bo0)));
    }
  }
}

extern "C" void kernel_launch(void* const* d_in, const int* in_sizes, int n_in,
                              void* d_out, int out_size, void* d_ws, size_t ws_size,
                              hipStream_t stream) {
  const float* xa      = (const float*)d_in[0];
  const float* xm      = (const float*)d_in[1];
  const int*   ema_src = (const int*)d_in[5];
  const int*   ema_dst = (const int*)d_in[6];
  const float* ema_w   = (const float*)d_in[7];
  const float* Wp_a    = (const float*)d_in[8];
  const float* bp_a    = (const float*)d_in[9];
  const float* Wr_ma   = (const float*)d_in[14];
  const float* br_ma   = (const float*)d_in[15];
  const float* Wc_a    = (const float*)d_in[16];
  const float* bc_a    = (const float*)d_in[17];
  const float* Wo      = (const float*)d_in[20];
  const float* bo      = (const float*)d_in[21];

  int NA = in_sizes[0] / 128;
  int E  = in_sizes[5];

  // workspace layout
  char* ws = (char*)d_ws;
  size_t off = 0;
  auto take = [&](size_t bytes) { char* p = ws + off; off = (off + bytes + 255) & ~(size_t)255; return p; };
  unsigned int* neighbf = (unsigned int*)take((size_t)NA * 64 * 2);      // bf16 [NA][64]
  float* sumw           = (float*)take((size_t)NA * 4);
  int* counts           = (int*)take((size_t)NA * 4);
  int* rowstart         = (int*)take((size_t)(NA + 1) * 4);
  int* cursor           = (int*)take((size_t)NA * 4);
  int* bsum             = (int*)take(1024 * 4);
  int* bexcl            = (int*)take(1024 * 4);
  unsigned long long* edges = (unsigned long long*)take((size_t)E * 8);
  unsigned short* Wcomb = (unsigned short*)take(128 * 192 * 2);
  float* beff           = (float*)take(128 * 4);
  float* vbr            = (float*)take(128 * 4);

  hipMemsetAsync(counts, 0, (size_t)NA * 4, stream);

  prep_kernel<<<128, 192, 0, stream>>>(Wp_a, bp_a, Wr_ma, br_ma, Wc_a, bc_a, Wcomb, beff, vbr);

  int ebn = (E + 255) / 256;
  hist_kernel<<<ebn, 256, 0, stream>>>(ema_dst, counts, E);

  int nb = (NA + 256) / 256;   // covers NA+1 scan positions
  scan_a<<<nb, 256, 0, stream>>>(counts, bsum, NA);
  scan_b<<<1, 1024, 0, stream>>>(bsum, bexcl, nb);
  scan_c<<<nb, 256, 0, stream>>>(counts, bexcl, rowstart, cursor, NA);

  scatter_kernel<<<ebn, 256, 0, stream>>>(ema_src, ema_dst, ema_w, cursor, edges, E);

  int gb = (NA + 3) / 4;
  gather_kernel<<<gb, 256, 0, stream>>>(xm, edges, rowstart, neighbf, sumw, NA);

  int ab = (NA + 63) / 64;
  acct_kernel<<<ab, 256, 0, stream>>>(xa, neighbf, sumw, Wcomb, beff, vbr, Wo, bo,
                                      (float*)d_out, NA);
}

// Round 3
// 498.035 us; speedup vs baseline: 1.2301x; 1.1557x over previous
//
#include <hip/hip_runtime.h>

// HeteroGraphSage on MI355X — round 3: latency-chain fixes.
//   neigh64[a] = sum_e w_e * x_m[src_e] ; sumw[a] = sum_e w_e
//   h_a = relu( Wcomb @ [x_a | neigh64] + sumw*vbr + beff )
//   out = sigmoid(Wo . h_a + bo)

typedef __attribute__((ext_vector_type(8))) short short8;
typedef __attribute__((ext_vector_type(4))) float f32x4;

__device__ inline unsigned short f32_bf16(float f) {
  unsigned int u = __float_as_uint(f);
  u += 0x7FFF + ((u >> 16) & 1);   // round-to-nearest-even
  return (unsigned short)(u >> 16);
}
__device__ inline unsigned int pk_bf16(float a, float b) {
  return (unsigned int)f32_bf16(a) | ((unsigned int)f32_bf16(b) << 16);
}

// ---- weight folding ---------------------------------------------------------
__global__ void prep_kernel(const float* __restrict__ Wp_a, const float* __restrict__ bp_a,
                            const float* __restrict__ Wr_ma, const float* __restrict__ br_ma,
                            const float* __restrict__ Wc_a, const float* __restrict__ bc_a,
                            unsigned short* __restrict__ Wcomb, float* __restrict__ beff,
                            float* __restrict__ vbr) {
  int col = blockIdx.x;
  int k = threadIdx.x;           // 0..191
  const float* wc = Wc_a + col * 256;
  float acc = 0.f;
  if (k < 128) {
#pragma unroll
    for (int j = 0; j < 128; ++j) acc += wc[j] * Wp_a[j * 128 + k];
  } else {
    int kk = k - 128;
#pragma unroll
    for (int j = 0; j < 128; ++j) acc += wc[128 + j] * Wr_ma[j * 64 + kk];
  }
  Wcomb[col * 192 + k] = f32_bf16(acc);
  if (k == 0) {
    float b = bc_a[col];
#pragma unroll
    for (int j = 0; j < 128; ++j) b += wc[j] * bp_a[j];
    beff[col] = b;
  } else if (k == 1) {
    float v = 0.f;
#pragma unroll
    for (int j = 0; j < 128; ++j) v += wc[128 + j] * br_ma[j];
    vbr[col] = v;
  }
}

// ---- CSR build: histogram, 3-phase exclusive scan, scatter ------------------
__global__ void hist_kernel(const int* __restrict__ dst, int* __restrict__ counts, int E) {
  int e = blockIdx.x * 256 + threadIdx.x;
  if (e < E) atomicAdd(&counts[dst[e]], 1);
}

__global__ void scan_a(const int* __restrict__ counts, int* __restrict__ bsum, int NA) {
  __shared__ int tmp[256];
  int t = threadIdx.x;
  int i = blockIdx.x * 256 + t;
  tmp[t] = (i < NA) ? counts[i] : 0;
  __syncthreads();
  for (int off = 128; off > 0; off >>= 1) {
    if (t < off) tmp[t] += tmp[t + off];
    __syncthreads();
  }
  if (t == 0) bsum[blockIdx.x] = tmp[0];
}

__global__ void scan_b(const int* __restrict__ bsum, int* __restrict__ bexcl, int nb) {
  __shared__ int tmp[1024];
  int t = threadIdx.x;
  int v = (t < nb) ? bsum[t] : 0;
  tmp[t] = v;
  __syncthreads();
  for (int off = 1; off < 1024; off <<= 1) {
    int x = (t >= off) ? tmp[t - off] : 0;
    __syncthreads();
    tmp[t] += x;
    __syncthreads();
  }
  bexcl[t] = tmp[t] - v;   // exclusive
}

__global__ void scan_c(const int* __restrict__ counts, const int* __restrict__ bexcl,
                       int* __restrict__ rowstart, int* __restrict__ cursor, int NA) {
  __shared__ int tmp[256];
  int t = threadIdx.x;
  int i = blockIdx.x * 256 + t;
  int v = (i < NA) ? counts[i] : 0;
  tmp[t] = v;
  __syncthreads();
  for (int off = 1; off < 256; off <<= 1) {
    int x = (t >= off) ? tmp[t - off] : 0;
    __syncthreads();
    tmp[t] += x;
    __syncthreads();
  }
  int excl = bexcl[blockIdx.x] + tmp[t] - v;
  if (i < NA) { rowstart[i] = excl; cursor[i] = excl; }
  else if (i == NA) { rowstart[NA] = excl; }
}

__global__ void scatter_kernel(const int* __restrict__ src, const int* __restrict__ dst,
                               const float* __restrict__ w, int* __restrict__ cursor,
                               unsigned long long* __restrict__ edges, int E) {
  int e = blockIdx.x * 256 + threadIdx.x;
  if (e >= E) return;
  int d = dst[e];
  int pos = atomicAdd(&cursor[d], 1);
  unsigned long long pk = (unsigned int)src[e] |
                          ((unsigned long long)__float_as_uint(w[e]) << 32);
  edges[pos] = pk;
}

// ---- neigh gather: one wave per account row, lane = feature, 4-wide pipeline
__global__ __launch_bounds__(256) void gather_kernel(
    const float* __restrict__ xm, const unsigned long long* __restrict__ edges,
    const int* __restrict__ rowstart, unsigned int* __restrict__ neighbf,
    float* __restrict__ sumw, int NA) {
  int wave = threadIdx.x >> 6, lane = threadIdx.x & 63;
  int a = blockIdx.x * 4 + wave;
  if (a >= NA) return;
  int s0 = rowstart[a], s1 = rowstart[a + 1];
  float acc = 0.f, ws = 0.f;
  int e = s0;
  for (; e + 4 <= s1; e += 4) {
    unsigned long long p0 = edges[e + 0], p1 = edges[e + 1],
                       p2 = edges[e + 2], p3 = edges[e + 3];
    float w0 = __uint_as_float((unsigned int)(p0 >> 32));
    float w1 = __uint_as_float((unsigned int)(p1 >> 32));
    float w2 = __uint_as_float((unsigned int)(p2 >> 32));
    float w3 = __uint_as_float((unsigned int)(p3 >> 32));
    float x0 = xm[(size_t)(unsigned int)p0 * 64 + lane];
    float x1 = xm[(size_t)(unsigned int)p1 * 64 + lane];
    float x2 = xm[(size_t)(unsigned int)p2 * 64 + lane];
    float x3 = xm[(size_t)(unsigned int)p3 * 64 + lane];
    acc += w0 * x0; acc += w1 * x1; acc += w2 * x2; acc += w3 * x3;
    ws += (w0 + w1) + (w2 + w3);
  }
  for (; e < s1; ++e) {
    unsigned long long p = edges[e];
    float w = __uint_as_float((unsigned int)(p >> 32));
    acc += w * xm[(size_t)(unsigned int)p * 64 + lane];
    ws += w;
  }
  float hi = __shfl_xor(acc, 1, 64);
  if ((lane & 1) == 0) {
    neighbf[(size_t)a * 32 + (lane >> 1)] = pk_bf16(acc, hi);
  }
  if (lane == 0) sumw[a] = ws;
}

// ---- fused account GEMM + head ---------------------------------------------
// 128 rows/block, 4 waves x 2 sequential 16-row tiles. A fragments loaded
// DIRECTLY from global (coalesced 32B/lane), B (Wcomb) staged once to LDS
// chunk-major for natural ds_read_b128. 16x16x32 bf16 MFMA (verified layouts).
__global__ __launch_bounds__(256) void acct_kernel(
    const float* __restrict__ xa, const unsigned int* __restrict__ neighbf,
    const float* __restrict__ sumw, const unsigned int* __restrict__ Wcomb32,
    const float* __restrict__ beff, const float* __restrict__ vbr,
    const float* __restrict__ Wo, const float* __restrict__ bo,
    float* __restrict__ out, int NA) {
  __shared__ unsigned int B_lds[24 * 128 * 4];   // 48 KB, [chunk c=s*4+quad][col][4 dwords]
  int tid = threadIdx.x;
  // stage B: thread i covers (c = i>>7, col = i&127); global uint4 idx = col*24+c
#pragma unroll
  for (int it = 0; it < 12; ++it) {
    int i = tid + it * 256;
    int c = i >> 7, col = i & 127;
    uint4 v = ((const uint4*)Wcomb32)[col * 24 + c];
    *((uint4*)&B_lds[i * 4]) = v;
  }
  __syncthreads();

  int wave = tid >> 6, lane = tid & 63;
  int n15 = lane & 15, quad = lane >> 4;
  float bo0 = bo[0];

  union U4 { uint4 u; short8 h; };

#pragma unroll
  for (int tile = 0; tile < 2; ++tile) {
    int rowbase = blockIdx.x * 128 + (wave * 2 + tile) * 16;
    int m = rowbase + n15;
    int mc = min(m, NA - 1);

    // A fragments: A[m=lane&15][k=quad*8+j]; s=0..3 from xa (f32->bf16), s=4..5 neighbf (bf16)
    U4 afr[6];
    const float* xrow = xa + (size_t)mc * 128 + quad * 8;
#pragma unroll
    for (int s = 0; s < 4; ++s) {
      float4 f0 = ((const float4*)(xrow + s * 32))[0];
      float4 f1 = ((const float4*)(xrow + s * 32))[1];
      afr[s].u = make_uint4(pk_bf16(f0.x, f0.y), pk_bf16(f0.z, f0.w),
                            pk_bf16(f1.x, f1.y), pk_bf16(f1.z, f1.w));
    }
#pragma unroll
    for (int s = 0; s < 2; ++s) {
      afr[4 + s].u = ((const uint4*)(neighbf + (size_t)mc * 32))[s * 4 + quad];
    }

    f32x4 acc[8];
#pragma unroll
    for (int t = 0; t < 8; ++t) acc[t] = (f32x4){0.f, 0.f, 0.f, 0.f};

#pragma unroll
    for (int s = 0; s < 6; ++s) {
#pragma unroll
      for (int t = 0; t < 8; ++t) {
        U4 bfr;
        bfr.u = *((const uint4*)&B_lds[((s * 4 + quad) * 128 + t * 16 + n15) * 4]);
        acc[t] = __builtin_amdgcn_mfma_f32_16x16x32_bf16(afr[s].h, bfr.h, acc[t], 0, 0, 0);
      }
    }

    // epilogue: C/D col = t*16+n15, row = quad*4+reg (verified)
    float sw[4];
#pragma unroll
    for (int r = 0; r < 4; ++r) {
      int grow = rowbase + quad * 4 + r;
      sw[r] = (grow < NA) ? sumw[grow] : 0.f;
    }
    float rowsum[4] = {0.f, 0.f, 0.f, 0.f};
#pragma unroll
    for (int t = 0; t < 8; ++t) {
      int col = t * 16 + n15;
      float be = beff[col], vb = vbr[col], wo = Wo[col];
#pragma unroll
      for (int r = 0; r < 4; ++r) {
        float h = acc[t][r] + be + sw[r] * vb;
        h = fmaxf(h, 0.f);
        rowsum[r] += h * wo;
      }
    }
#pragma unroll
    for (int msk = 1; msk <= 8; msk <<= 1) {
#pragma unroll
      for (int r = 0; r < 4; ++r) rowsum[r] += __shfl_xor(rowsum[r], msk, 64);
    }
    if (n15 == 0) {
#pragma unroll
      for (int r = 0; r < 4; ++r) {
        int grow = rowbase + quad * 4 + r;
        if (grow < NA) out[grow] = 1.0f / (1.0f + __expf(-(rowsum[r] + bo0)));
      }
    }
  }
}

extern "C" void kernel_launch(void* const* d_in, const int* in_sizes, int n_in,
                              void* d_out, int out_size, void* d_ws, size_t ws_size,
                              hipStream_t stream) {
  const float* xa      = (const float*)d_in[0];
  const float* xm      = (const float*)d_in[1];
  const int*   ema_src = (const int*)d_in[5];
  const int*   ema_dst = (const int*)d_in[6];
  const float* ema_w   = (const float*)d_in[7];
  const float* Wp_a    = (const float*)d_in[8];
  const float* bp_a    = (const float*)d_in[9];
  const float* Wr_ma   = (const float*)d_in[14];
  const float* br_ma   = (const float*)d_in[15];
  const float* Wc_a    = (const float*)d_in[16];
  const float* bc_a    = (const float*)d_in[17];
  const float* Wo      = (const float*)d_in[20];
  const float* bo      = (const float*)d_in[21];

  int NA = in_sizes[0] / 128;
  int E  = in_sizes[5];

  char* ws = (char*)d_ws;
  size_t off = 0;
  auto take = [&](size_t bytes) { char* p = ws + off; off = (off + bytes + 255) & ~(size_t)255; return p; };
  unsigned int* neighbf = (unsigned int*)take((size_t)NA * 64 * 2);      // bf16 [NA][64]
  float* sumw           = (float*)take((size_t)NA * 4);
  int* counts           = (int*)take((size_t)NA * 4);
  int* rowstart         = (int*)take((size_t)(NA + 1) * 4);
  int* cursor           = (int*)take((size_t)NA * 4);
  int* bsum             = (int*)take(1024 * 4);
  int* bexcl            = (int*)take(1024 * 4);
  unsigned long long* edges = (unsigned long long*)take((size_t)E * 8);
  unsigned short* Wcomb = (unsigned short*)take(128 * 192 * 2);
  float* beff           = (float*)take(128 * 4);
  float* vbr            = (float*)take(128 * 4);

  hipMemsetAsync(counts, 0, (size_t)NA * 4, stream);

  prep_kernel<<<128, 192, 0, stream>>>(Wp_a, bp_a, Wr_ma, br_ma, Wc_a, bc_a, Wcomb, beff, vbr);

  int ebn = (E + 255) / 256;
  hist_kernel<<<ebn, 256, 0, stream>>>(ema_dst, counts, E);

  int nb = (NA + 256) / 256;
  scan_a<<<nb, 256, 0, stream>>>(counts, bsum, NA);
  scan_b<<<1, 1024, 0, stream>>>(bsum, bexcl, nb);
  scan_c<<<nb, 256, 0, stream>>>(counts, bexcl, rowstart, cursor, NA);

  scatter_kernel<<<ebn, 256, 0, stream>>>(ema_src, ema_dst, ema_w, cursor, edges, E);

  int gb = (NA + 3) / 4;
  gather_kernel<<<gb, 256, 0, stream>>>(xm, edges, rowstart, neighbf, sumw, NA);

  int ab = (NA + 127) / 128;
  acct_kernel<<<ab, 256, 0, stream>>>(xa, neighbf, sumw, (const unsigned int*)Wcomb,
                                      beff, vbr, Wo, bo, (float*)d_out, NA);
}

// Round 4
// 415.883 us; speedup vs baseline: 1.4730x; 1.1975x over previous
//
#include <hip/hip_runtime.h>

// HeteroGraphSage on MI355X — round 4: drain-probe + prep rewrite + batched gather.
//   neigh64[a] = sum_e w_e * x_m[src_e] ; sumw[a] = sum_e w_e
//   h_a = relu( Wcomb @ [x_a | neigh64] + sumw*vbr + beff )
//   out = sigmoid(Wo . h_a + bo)

typedef __attribute__((ext_vector_type(8))) short short8;
typedef __attribute__((ext_vector_type(4))) float f32x4;

__device__ inline unsigned short f32_bf16(float f) {
  unsigned int u = __float_as_uint(f);
  u += 0x7FFF + ((u >> 16) & 1);   // round-to-nearest-even
  return (unsigned short)(u >> 16);
}
__device__ inline unsigned int pk_bf16(float a, float b) {
  return (unsigned int)f32_bf16(a) | ((unsigned int)f32_bf16(b) << 16);
}

// ---- drain probe: trivial first kernel; if its dur is large, the harness's
// restore/poison traffic is draining during our first dispatch window (T1).
__global__ void fence0_kernel(const float* __restrict__ xa, float* __restrict__ probe) {
  int lane = threadIdx.x & 63;
  probe[lane] = xa[lane] * 0.5f;
}

// ---- weight folding: 128 blocks (one per col) x 256 threads ---------------
// wave 0,1: Wcomb[col][k<128] from Wp_a; wave 2: Wcomb[col][128+kk] from Wr_ma;
// wave 3: shuffle-reduce beff[col], vbr[col].
__global__ __launch_bounds__(256) void prep_kernel(
    const float* __restrict__ Wp_a, const float* __restrict__ bp_a,
    const float* __restrict__ Wr_ma, const float* __restrict__ br_ma,
    const float* __restrict__ Wc_a, const float* __restrict__ bc_a,
    unsigned short* __restrict__ Wcomb, float* __restrict__ beff,
    float* __restrict__ vbr) {
  __shared__ float wc_s[256];
  int col = blockIdx.x;
  int t = threadIdx.x;
  wc_s[t] = Wc_a[col * 256 + t];
  __syncthreads();
  int wave = t >> 6, lane = t & 63;
  if (wave < 2) {
    int k = t;   // 0..127
    float acc = 0.f;
#pragma unroll
    for (int j = 0; j < 128; j += 4) {
      float a0 = Wp_a[(j + 0) * 128 + k];
      float a1 = Wp_a[(j + 1) * 128 + k];
      float a2 = Wp_a[(j + 2) * 128 + k];
      float a3 = Wp_a[(j + 3) * 128 + k];
      acc += wc_s[j] * a0 + wc_s[j + 1] * a1 + wc_s[j + 2] * a2 + wc_s[j + 3] * a3;
    }
    Wcomb[col * 192 + k] = f32_bf16(acc);
  } else if (wave == 2) {
    int kk = lane;   // 0..63
    float acc = 0.f;
#pragma unroll
    for (int j = 0; j < 128; j += 4) {
      float a0 = Wr_ma[(j + 0) * 64 + kk];
      float a1 = Wr_ma[(j + 1) * 64 + kk];
      float a2 = Wr_ma[(j + 2) * 64 + kk];
      float a3 = Wr_ma[(j + 3) * 64 + kk];
      acc += wc_s[128 + j] * a0 + wc_s[129 + j] * a1 + wc_s[130 + j] * a2 + wc_s[131 + j] * a3;
    }
    Wcomb[col * 192 + 128 + kk] = f32_bf16(acc);
  } else {
    float v1 = wc_s[lane] * bp_a[lane] + wc_s[lane + 64] * bp_a[lane + 64];
    float v2 = wc_s[128 + lane] * br_ma[lane] + wc_s[192 + lane] * br_ma[lane + 64];
#pragma unroll
    for (int m = 1; m <= 32; m <<= 1) {
      v1 += __shfl_xor(v1, m, 64);
      v2 += __shfl_xor(v2, m, 64);
    }
    if (lane == 0) { beff[col] = v1 + bc_a[col]; vbr[col] = v2; }
  }
}

// ---- CSR build: histogram, 3-phase exclusive scan, scatter ------------------
__global__ void hist_kernel(const int* __restrict__ dst, int* __restrict__ counts, int E) {
  int e = blockIdx.x * 256 + threadIdx.x;
  if (e < E) atomicAdd(&counts[dst[e]], 1);
}

__global__ void scan_a(const int* __restrict__ counts, int* __restrict__ bsum, int NA) {
  __shared__ int tmp[256];
  int t = threadIdx.x;
  int i = blockIdx.x * 256 + t;
  tmp[t] = (i < NA) ? counts[i] : 0;
  __syncthreads();
  for (int off = 128; off > 0; off >>= 1) {
    if (t < off) tmp[t] += tmp[t + off];
    __syncthreads();
  }
  if (t == 0) bsum[blockIdx.x] = tmp[0];
}

__global__ void scan_b(const int* __restrict__ bsum, int* __restrict__ bexcl, int nb) {
  __shared__ int tmp[1024];
  int t = threadIdx.x;
  int v = (t < nb) ? bsum[t] : 0;
  tmp[t] = v;
  __syncthreads();
  for (int off = 1; off < 1024; off <<= 1) {
    int x = (t >= off) ? tmp[t - off] : 0;
    __syncthreads();
    tmp[t] += x;
    __syncthreads();
  }
  bexcl[t] = tmp[t] - v;   // exclusive
}

__global__ void scan_c(const int* __restrict__ counts, const int* __restrict__ bexcl,
                       int* __restrict__ rowstart, int* __restrict__ cursor, int NA) {
  __shared__ int tmp[256];
  int t = threadIdx.x;
  int i = blockIdx.x * 256 + t;
  int v = (i < NA) ? counts[i] : 0;
  tmp[t] = v;
  __syncthreads();
  for (int off = 1; off < 256; off <<= 1) {
    int x = (t >= off) ? tmp[t - off] : 0;
    __syncthreads();
    tmp[t] += x;
    __syncthreads();
  }
  int excl = bexcl[blockIdx.x] + tmp[t] - v;
  if (i < NA) { rowstart[i] = excl; cursor[i] = excl; }
  else if (i == NA) { rowstart[NA] = excl; }
}

__global__ void scatter_kernel(const int* __restrict__ src, const int* __restrict__ dst,
                               const float* __restrict__ w, int* __restrict__ cursor,
                               unsigned long long* __restrict__ edges, int E) {
  int e = blockIdx.x * 256 + threadIdx.x;
  if (e >= E) return;
  int d = dst[e];
  int pos = atomicAdd(&cursor[d], 1);
  unsigned long long pk = (unsigned int)src[e] |
                          ((unsigned long long)__float_as_uint(w[e]) << 32);
  edges[pos] = pk;
}

// ---- neigh gather: one wave per account row, lane = feature ----------------
// avg degree ~5 -> handle a row's edges in PREDICATED batches of 8 so all xm
// gathers issue in one latency wave (no serial 1-wide tail).
__global__ __launch_bounds__(256) void gather_kernel(
    const float* __restrict__ xm, const unsigned long long* __restrict__ edges,
    const int* __restrict__ rowstart, unsigned int* __restrict__ neighbf,
    float* __restrict__ sumw, int NA) {
  int wave = threadIdx.x >> 6, lane = threadIdx.x & 63;
  int a = blockIdx.x * 4 + wave;
  if (a >= NA) return;
  int s0 = rowstart[a], s1 = rowstart[a + 1];
  float acc = 0.f, ws = 0.f;
  for (int e0 = s0; e0 < s1; e0 += 8) {
#pragma unroll
    for (int u = 0; u < 8; ++u) {
      int e = e0 + u;
      bool valid = e < s1;
      unsigned long long p = edges[valid ? e : s0];
      float w = valid ? __uint_as_float((unsigned int)(p >> 32)) : 0.f;
      int s = (int)(p & 0xffffffffu);
      float x = xm[(size_t)s * 64 + lane];
      acc += w * x;
      ws += w;
    }
  }
  float hi = __shfl_xor(acc, 1, 64);
  if ((lane & 1) == 0) {
    neighbf[(size_t)a * 32 + (lane >> 1)] = pk_bf16(acc, hi);
  }
  if (lane == 0) sumw[a] = ws;
}

// ---- fused account GEMM + head (unchanged structure from round 3) ----------
__global__ __launch_bounds__(256) void acct_kernel(
    const float* __restrict__ xa, const unsigned int* __restrict__ neighbf,
    const float* __restrict__ sumw, const unsigned int* __restrict__ Wcomb32,
    const float* __restrict__ beff, const float* __restrict__ vbr,
    const float* __restrict__ Wo, const float* __restrict__ bo,
    float* __restrict__ out, int NA) {
  __shared__ unsigned int B_lds[24 * 128 * 4];   // 48 KB, [chunk c=s*4+quad][col][4 dwords]
  int tid = threadIdx.x;
#pragma unroll
  for (int it = 0; it < 12; ++it) {
    int i = tid + it * 256;
    int c = i >> 7, col = i & 127;
    uint4 v = ((const uint4*)Wcomb32)[col * 24 + c];
    *((uint4*)&B_lds[i * 4]) = v;
  }
  __syncthreads();

  int wave = tid >> 6, lane = tid & 63;
  int n15 = lane & 15, quad = lane >> 4;
  float bo0 = bo[0];

  union U4 { uint4 u; short8 h; };

#pragma unroll
  for (int tile = 0; tile < 2; ++tile) {
    int rowbase = blockIdx.x * 128 + (wave * 2 + tile) * 16;
    int m = rowbase + n15;
    int mc = min(m, NA - 1);

    U4 afr[6];
    const float* xrow = xa + (size_t)mc * 128 + quad * 8;
#pragma unroll
    for (int s = 0; s < 4; ++s) {
      float4 f0 = ((const float4*)(xrow + s * 32))[0];
      float4 f1 = ((const float4*)(xrow + s * 32))[1];
      afr[s].u = make_uint4(pk_bf16(f0.x, f0.y), pk_bf16(f0.z, f0.w),
                            pk_bf16(f1.x, f1.y), pk_bf16(f1.z, f1.w));
    }
#pragma unroll
    for (int s = 0; s < 2; ++s) {
      afr[4 + s].u = ((const uint4*)(neighbf + (size_t)mc * 32))[s * 4 + quad];
    }

    f32x4 acc[8];
#pragma unroll
    for (int t = 0; t < 8; ++t) acc[t] = (f32x4){0.f, 0.f, 0.f, 0.f};

#pragma unroll
    for (int s = 0; s < 6; ++s) {
#pragma unroll
      for (int t = 0; t < 8; ++t) {
        U4 bfr;
        bfr.u = *((const uint4*)&B_lds[((s * 4 + quad) * 128 + t * 16 + n15) * 4]);
        acc[t] = __builtin_amdgcn_mfma_f32_16x16x32_bf16(afr[s].h, bfr.h, acc[t], 0, 0, 0);
      }
    }

    float sw[4];
#pragma unroll
    for (int r = 0; r < 4; ++r) {
      int grow = rowbase + quad * 4 + r;
      sw[r] = (grow < NA) ? sumw[grow] : 0.f;
    }
    float rowsum[4] = {0.f, 0.f, 0.f, 0.f};
#pragma unroll
    for (int t = 0; t < 8; ++t) {
      int col = t * 16 + n15;
      float be = beff[col], vb = vbr[col], wo = Wo[col];
#pragma unroll
      for (int r = 0; r < 4; ++r) {
        float h = acc[t][r] + be + sw[r] * vb;
        h = fmaxf(h, 0.f);
        rowsum[r] += h * wo;
      }
    }
#pragma unroll
    for (int msk = 1; msk <= 8; msk <<= 1) {
#pragma unroll
      for (int r = 0; r < 4; ++r) rowsum[r] += __shfl_xor(rowsum[r], msk, 64);
    }
    if (n15 == 0) {
#pragma unroll
      for (int r = 0; r < 4; ++r) {
        int grow = rowbase + quad * 4 + r;
        if (grow < NA) out[grow] = 1.0f / (1.0f + __expf(-(rowsum[r] + bo0)));
      }
    }
  }
}

extern "C" void kernel_launch(void* const* d_in, const int* in_sizes, int n_in,
                              void* d_out, int out_size, void* d_ws, size_t ws_size,
                              hipStream_t stream) {
  const float* xa      = (const float*)d_in[0];
  const float* xm      = (const float*)d_in[1];
  const int*   ema_src = (const int*)d_in[5];
  const int*   ema_dst = (const int*)d_in[6];
  const float* ema_w   = (const float*)d_in[7];
  const float* Wp_a    = (const float*)d_in[8];
  const float* bp_a    = (const float*)d_in[9];
  const float* Wr_ma   = (const float*)d_in[14];
  const float* br_ma   = (const float*)d_in[15];
  const float* Wc_a    = (const float*)d_in[16];
  const float* bc_a    = (const float*)d_in[17];
  const float* Wo      = (const float*)d_in[20];
  const float* bo      = (const float*)d_in[21];

  int NA = in_sizes[0] / 128;
  int E  = in_sizes[5];

  char* ws = (char*)d_ws;
  size_t off = 0;
  auto take = [&](size_t bytes) { char* p = ws + off; off = (off + bytes + 255) & ~(size_t)255; return p; };
  unsigned int* neighbf = (unsigned int*)take((size_t)NA * 64 * 2);      // bf16 [NA][64]
  float* sumw           = (float*)take((size_t)NA * 4);
  int* counts           = (int*)take((size_t)NA * 4);
  int* rowstart         = (int*)take((size_t)(NA + 1) * 4);
  int* cursor           = (int*)take((size_t)NA * 4);
  int* bsum             = (int*)take(1024 * 4);
  int* bexcl            = (int*)take(1024 * 4);
  unsigned long long* edges = (unsigned long long*)take((size_t)E * 8);
  unsigned short* Wcomb = (unsigned short*)take(128 * 192 * 2);
  float* beff           = (float*)take(128 * 4);
  float* vbr            = (float*)take(128 * 4);
  float* probe          = (float*)take(64 * 4);

  // drain probe first: if the harness's restore/poison traffic stalls our
  // first dispatch, THIS kernel absorbs it (diagnostic, ~2us otherwise)
  fence0_kernel<<<1, 64, 0, stream>>>(xa, probe);

  hipMemsetAsync(counts, 0, (size_t)NA * 4, stream);

  int ebn = (E + 255) / 256;
  hist_kernel<<<ebn, 256, 0, stream>>>(ema_dst, counts, E);

  prep_kernel<<<128, 256, 0, stream>>>(Wp_a, bp_a, Wr_ma, br_ma, Wc_a, bc_a, Wcomb, beff, vbr);

  int nb = (NA + 256) / 256;
  scan_a<<<nb, 256, 0, stream>>>(counts, bsum, NA);
  scan_b<<<1, 1024, 0, stream>>>(bsum, bexcl, nb);
  scan_c<<<nb, 256, 0, stream>>>(counts, bexcl, rowstart, cursor, NA);

  scatter_kernel<<<ebn, 256, 0, stream>>>(ema_src, ema_dst, ema_w, cursor, edges, E);

  int gb = (NA + 3) / 4;
  gather_kernel<<<gb, 256, 0, stream>>>(xm, edges, rowstart, neighbf, sumw, NA);

  int ab = (NA + 127) / 128;
  acct_kernel<<<ab, 256, 0, stream>>>(xa, neighbf, sumw, (const unsigned int*)Wcomb,
                                      beff, vbr, Wo, bo, (float*)d_out, NA);
}

// Round 6
// 393.209 us; speedup vs baseline: 1.5580x; 1.0577x over previous
//
#include <hip/hip_runtime.h>

// HeteroGraphSage on MI355X — round 5 (resubmit after infra timeout):
// bf16 xm + 2-edges-per-wave gather.
//   neigh64[a] = sum_e w_e * x_m[src_e] ; sumw[a] = sum_e w_e
//   h_a = relu( Wcomb @ [x_a | neigh64] + sumw*vbr + beff )
//   out = sigmoid(Wo . h_a + bo)

typedef __attribute__((ext_vector_type(8))) short short8;
typedef __attribute__((ext_vector_type(4))) float f32x4;

__device__ inline unsigned short f32_bf16(float f) {
  unsigned int u = __float_as_uint(f);
  u += 0x7FFF + ((u >> 16) & 1);   // round-to-nearest-even
  return (unsigned short)(u >> 16);
}
__device__ inline unsigned int pk_bf16(float a, float b) {
  return (unsigned int)f32_bf16(a) | ((unsigned int)f32_bf16(b) << 16);
}

// ---- drain probe / first-dispatch absorber (diagnostic, ~2us normally) -----
__global__ void fence0_kernel(const float* __restrict__ xa, float* __restrict__ probe) {
  int lane = threadIdx.x & 63;
  probe[lane] = xa[lane] * 0.5f;
}

// ---- xm f32 -> packed bf16 pairs: [NM][32] uints ---------------------------
__global__ void cvt_xm_kernel(const float* __restrict__ xm,
                              unsigned int* __restrict__ xmbf, int npairs) {
  int i = blockIdx.x * 256 + threadIdx.x;
  if (i < npairs) {
    float2 v = ((const float2*)xm)[i];
    xmbf[i] = pk_bf16(v.x, v.y);
  }
}

// ---- weight folding: 128 blocks (one per col) x 256 threads ----------------
__global__ __launch_bounds__(256) void prep_kernel(
    const float* __restrict__ Wp_a, const float* __restrict__ bp_a,
    const float* __restrict__ Wr_ma, const float* __restrict__ br_ma,
    const float* __restrict__ Wc_a, const float* __restrict__ bc_a,
    unsigned short* __restrict__ Wcomb, float* __restrict__ beff,
    float* __restrict__ vbr) {
  __shared__ float wc_s[256];
  int col = blockIdx.x;
  int t = threadIdx.x;
  wc_s[t] = Wc_a[col * 256 + t];
  __syncthreads();
  int wave = t >> 6, lane = t & 63;
  if (wave < 2) {
    int k = t;   // 0..127
    float acc = 0.f;
#pragma unroll
    for (int j = 0; j < 128; j += 4) {
      float a0 = Wp_a[(j + 0) * 128 + k];
      float a1 = Wp_a[(j + 1) * 128 + k];
      float a2 = Wp_a[(j + 2) * 128 + k];
      float a3 = Wp_a[(j + 3) * 128 + k];
      acc += wc_s[j] * a0 + wc_s[j + 1] * a1 + wc_s[j + 2] * a2 + wc_s[j + 3] * a3;
    }
    Wcomb[col * 192 + k] = f32_bf16(acc);
  } else if (wave == 2) {
    int kk = lane;   // 0..63
    float acc = 0.f;
#pragma unroll
    for (int j = 0; j < 128; j += 4) {
      float a0 = Wr_ma[(j + 0) * 64 + kk];
      float a1 = Wr_ma[(j + 1) * 64 + kk];
      float a2 = Wr_ma[(j + 2) * 64 + kk];
      float a3 = Wr_ma[(j + 3) * 64 + kk];
      acc += wc_s[128 + j] * a0 + wc_s[129 + j] * a1 + wc_s[130 + j] * a2 + wc_s[131 + j] * a3;
    }
    Wcomb[col * 192 + 128 + kk] = f32_bf16(acc);
  } else {
    float v1 = wc_s[lane] * bp_a[lane] + wc_s[lane + 64] * bp_a[lane + 64];
    float v2 = wc_s[128 + lane] * br_ma[lane] + wc_s[192 + lane] * br_ma[lane + 64];
#pragma unroll
    for (int m = 1; m <= 32; m <<= 1) {
      v1 += __shfl_xor(v1, m, 64);
      v2 += __shfl_xor(v2, m, 64);
    }
    if (lane == 0) { beff[col] = v1 + bc_a[col]; vbr[col] = v2; }
  }
}

// ---- CSR build: histogram, 3-phase exclusive scan, scatter ------------------
__global__ void hist_kernel(const int* __restrict__ dst, int* __restrict__ counts, int E) {
  int e = blockIdx.x * 256 + threadIdx.x;
  if (e < E) atomicAdd(&counts[dst[e]], 1);
}

__global__ void scan_a(const int* __restrict__ counts, int* __restrict__ bsum, int NA) {
  __shared__ int tmp[256];
  int t = threadIdx.x;
  int i = blockIdx.x * 256 + t;
  tmp[t] = (i < NA) ? counts[i] : 0;
  __syncthreads();
  for (int off = 128; off > 0; off >>= 1) {
    if (t < off) tmp[t] += tmp[t + off];
    __syncthreads();
  }
  if (t == 0) bsum[blockIdx.x] = tmp[0];
}

__global__ void scan_b(const int* __restrict__ bsum, int* __restrict__ bexcl, int nb) {
  __shared__ int tmp[1024];
  int t = threadIdx.x;
  int v = (t < nb) ? bsum[t] : 0;
  tmp[t] = v;
  __syncthreads();
  for (int off = 1; off < 1024; off <<= 1) {
    int x = (t >= off) ? tmp[t - off] : 0;
    __syncthreads();
    tmp[t] += x;
    __syncthreads();
  }
  bexcl[t] = tmp[t] - v;   // exclusive
}

__global__ void scan_c(const int* __restrict__ counts, const int* __restrict__ bexcl,
                       int* __restrict__ rowstart, int* __restrict__ cursor, int NA) {
  __shared__ int tmp[256];
  int t = threadIdx.x;
  int i = blockIdx.x * 256 + t;
  int v = (i < NA) ? counts[i] : 0;
  tmp[t] = v;
  __syncthreads();
  for (int off = 1; off < 256; off <<= 1) {
    int x = (t >= off) ? tmp[t - off] : 0;
    __syncthreads();
    tmp[t] += x;
    __syncthreads();
  }
  int excl = bexcl[blockIdx.x] + tmp[t] - v;
  if (i < NA) { rowstart[i] = excl; cursor[i] = excl; }
  else if (i == NA) { rowstart[NA] = excl; }
}

__global__ void scatter_kernel(const int* __restrict__ src, const int* __restrict__ dst,
                               const float* __restrict__ w, int* __restrict__ cursor,
                               unsigned long long* __restrict__ edges, int E) {
  int e = blockIdx.x * 256 + threadIdx.x;
  if (e >= E) return;
  int d = dst[e];
  int pos = atomicAdd(&cursor[d], 1);
  unsigned long long pk = (unsigned int)src[e] |
                          ((unsigned long long)__float_as_uint(w[e]) << 32);
  edges[pos] = pk;
}

// ---- neigh gather: one wave per row; 2 edges per iteration (half-wave each);
// lane handles a feature PAIR via one uint (2xbf16) load. Final cross-half
// shfl merge; lanes<32 already hold the packed-pair layout neighbf wants.
__global__ __launch_bounds__(256) void gather_kernel(
    const unsigned int* __restrict__ xmbf, const unsigned long long* __restrict__ edges,
    const int* __restrict__ rowstart, unsigned int* __restrict__ neighbf,
    float* __restrict__ sumw, int NA) {
  int wave = threadIdx.x >> 6, lane = threadIdx.x & 63;
  int a = blockIdx.x * 4 + wave;
  if (a >= NA) return;
  int half = lane >> 5;   // which edge of the pair this half-wave takes
  int fp = lane & 31;     // feature-pair index: feats (2fp, 2fp+1)
  int s0 = rowstart[a], s1 = rowstart[a + 1];
  float accx = 0.f, accy = 0.f, ws = 0.f;
  for (int e0 = s0; e0 < s1; e0 += 8) {
#pragma unroll
    for (int k = 0; k < 4; ++k) {
      int e = e0 + k * 2 + half;
      bool valid = e < s1;
      unsigned long long p = edges[valid ? e : s0];
      float w = valid ? __uint_as_float((unsigned int)(p >> 32)) : 0.f;
      unsigned int s = (unsigned int)p;
      unsigned int xp = xmbf[(size_t)s * 32 + fp];
      float x0 = __uint_as_float(xp << 16);            // feat 2fp
      float x1 = __uint_as_float(xp & 0xffff0000u);    // feat 2fp+1
      accx += w * x0;
      accy += w * x1;
      ws += w;
    }
  }
  accx += __shfl_xor(accx, 32, 64);
  accy += __shfl_xor(accy, 32, 64);
  ws   += __shfl_xor(ws, 32, 64);   // halves processed disjoint edges
  if (half == 0) {
    neighbf[(size_t)a * 32 + fp] = pk_bf16(accx, accy);
    if (fp == 0) sumw[a] = ws;
  }
}

// ---- fused account GEMM + head (round-3 structure) -------------------------
__global__ __launch_bounds__(256) void acct_kernel(
    const float* __restrict__ xa, const unsigned int* __restrict__ neighbf,
    const float* __restrict__ sumw, const unsigned int* __restrict__ Wcomb32,
    const float* __restrict__ beff, const float* __restrict__ vbr,
    const float* __restrict__ Wo, const float* __restrict__ bo,
    float* __restrict__ out, int NA) {
  __shared__ unsigned int B_lds[24 * 128 * 4];   // 48 KB, [chunk c=s*4+quad][col][4 dwords]
  int tid = threadIdx.x;
#pragma unroll
  for (int it = 0; it < 12; ++it) {
    int i = tid + it * 256;
    int c = i >> 7, col = i & 127;
    uint4 v = ((const uint4*)Wcomb32)[col * 24 + c];
    *((uint4*)&B_lds[i * 4]) = v;
  }
  __syncthreads();

  int wave = tid >> 6, lane = tid & 63;
  int n15 = lane & 15, quad = lane >> 4;
  float bo0 = bo[0];

  union U4 { uint4 u; short8 h; };

#pragma unroll
  for (int tile = 0; tile < 2; ++tile) {
    int rowbase = blockIdx.x * 128 + (wave * 2 + tile) * 16;
    int m = rowbase + n15;
    int mc = min(m, NA - 1);

    U4 afr[6];
    const float* xrow = xa + (size_t)mc * 128 + quad * 8;
#pragma unroll
    for (int s = 0; s < 4; ++s) {
      float4 f0 = ((const float4*)(xrow + s * 32))[0];
      float4 f1 = ((const float4*)(xrow + s * 32))[1];
      afr[s].u = make_uint4(pk_bf16(f0.x, f0.y), pk_bf16(f0.z, f0.w),
                            pk_bf16(f1.x, f1.y), pk_bf16(f1.z, f1.w));
    }
#pragma unroll
    for (int s = 0; s < 2; ++s) {
      afr[4 + s].u = ((const uint4*)(neighbf + (size_t)mc * 32))[s * 4 + quad];
    }

    f32x4 acc[8];
#pragma unroll
    for (int t = 0; t < 8; ++t) acc[t] = (f32x4){0.f, 0.f, 0.f, 0.f};

#pragma unroll
    for (int s = 0; s < 6; ++s) {
#pragma unroll
      for (int t = 0; t < 8; ++t) {
        U4 bfr;
        bfr.u = *((const uint4*)&B_lds[((s * 4 + quad) * 128 + t * 16 + n15) * 4]);
        acc[t] = __builtin_amdgcn_mfma_f32_16x16x32_bf16(afr[s].h, bfr.h, acc[t], 0, 0, 0);
      }
    }

    float sw[4];
#pragma unroll
    for (int r = 0; r < 4; ++r) {
      int grow = rowbase + quad * 4 + r;
      sw[r] = (grow < NA) ? sumw[grow] : 0.f;
    }
    float rowsum[4] = {0.f, 0.f, 0.f, 0.f};
#pragma unroll
    for (int t = 0; t < 8; ++t) {
      int col = t * 16 + n15;
      float be = beff[col], vb = vbr[col], wo = Wo[col];
#pragma unroll
      for (int r = 0; r < 4; ++r) {
        float h = acc[t][r] + be + sw[r] * vb;
        h = fmaxf(h, 0.f);
        rowsum[r] += h * wo;
      }
    }
#pragma unroll
    for (int msk = 1; msk <= 8; msk <<= 1) {
#pragma unroll
      for (int r = 0; r < 4; ++r) rowsum[r] += __shfl_xor(rowsum[r], msk, 64);
    }
    if (n15 == 0) {
#pragma unroll
      for (int r = 0; r < 4; ++r) {
        int grow = rowbase + quad * 4 + r;
        if (grow < NA) out[grow] = 1.0f / (1.0f + __expf(-(rowsum[r] + bo0)));
      }
    }
  }
}

extern "C" void kernel_launch(void* const* d_in, const int* in_sizes, int n_in,
                              void* d_out, int out_size, void* d_ws, size_t ws_size,
                              hipStream_t stream) {
  const float* xa      = (const float*)d_in[0];
  const float* xm      = (const float*)d_in[1];
  const int*   ema_src = (const int*)d_in[5];
  const int*   ema_dst = (const int*)d_in[6];
  const float* ema_w   = (const float*)d_in[7];
  const float* Wp_a    = (const float*)d_in[8];
  const float* bp_a    = (const float*)d_in[9];
  const float* Wr_ma   = (const float*)d_in[14];
  const float* br_ma   = (const float*)d_in[15];
  const float* Wc_a    = (const float*)d_in[16];
  const float* bc_a    = (const float*)d_in[17];
  const float* Wo      = (const float*)d_in[20];
  const float* bo      = (const float*)d_in[21];

  int NA = in_sizes[0] / 128;
  int NM = in_sizes[1] / 64;
  int E  = in_sizes[5];

  char* ws = (char*)d_ws;
  size_t off = 0;
  auto take = [&](size_t bytes) { char* p = ws + off; off = (off + bytes + 255) & ~(size_t)255; return p; };
  unsigned int* neighbf = (unsigned int*)take((size_t)NA * 32 * 4);      // bf16 pairs [NA][32]
  unsigned int* xmbf    = (unsigned int*)take((size_t)NM * 32 * 4);      // bf16 pairs [NM][32]
  float* sumw           = (float*)take((size_t)NA * 4);
  int* counts           = (int*)take((size_t)NA * 4);
  int* rowstart         = (int*)take((size_t)(NA + 1) * 4);
  int* cursor           = (int*)take((size_t)NA * 4);
  int* bsum             = (int*)take(1024 * 4);
  int* bexcl            = (int*)take(1024 * 4);
  unsigned long long* edges = (unsigned long long*)take((size_t)E * 8);
  unsigned short* Wcomb = (unsigned short*)take(128 * 192 * 2);
  float* beff           = (float*)take(128 * 4);
  float* vbr            = (float*)take(128 * 4);
  float* probe          = (float*)take(64 * 4);

  fence0_kernel<<<1, 64, 0, stream>>>(xa, probe);

  hipMemsetAsync(counts, 0, (size_t)NA * 4, stream);

  int npairs = NM * 32;
  cvt_xm_kernel<<<(npairs + 255) / 256, 256, 0, stream>>>(xm, xmbf, npairs);

  int ebn = (E + 255) / 256;
  hist_kernel<<<ebn, 256, 0, stream>>>(ema_dst, counts, E);

  prep_kernel<<<128, 256, 0, stream>>>(Wp_a, bp_a, Wr_ma, br_ma, Wc_a, bc_a, Wcomb, beff, vbr);

  int nb = (NA + 256) / 256;
  scan_a<<<nb, 256, 0, stream>>>(counts, bsum, NA);
  scan_b<<<1, 1024, 0, stream>>>(bsum, bexcl, nb);
  scan_c<<<nb, 256, 0, stream>>>(counts, bexcl, rowstart, cursor, NA);

  scatter_kernel<<<ebn, 256, 0, stream>>>(ema_src, ema_dst, ema_w, cursor, edges, E);

  int gb = (NA + 3) / 4;
  gather_kernel<<<gb, 256, 0, stream>>>(xmbf, edges, rowstart, neighbf, sumw, NA);

  int ab = (NA + 127) / 128;
  acct_kernel<<<ab, 256, 0, stream>>>(xa, neighbf, sumw, (const unsigned int*)Wcomb,
                                      beff, vbr, Wo, bo, (float*)d_out, NA);
}